// Round 2
// baseline (1567.060 us; speedup 1.0000x reference)
//
#include <hip/hip_runtime.h>
#include <stdint.h>

// ---------------------------------------------------------------------------
// AttentionBlock (MLA-style) on gfx950. Round 2: compact-workspace version.
// R1 aborted with an HSA memory fault; the only unchecked assumption was the
// 256 MiB workspace footprint. This version fits in 104 MiB via phase-based
// aliasing + FFN split into two N-halves. Compute structure unchanged.
// ---------------------------------------------------------------------------

typedef unsigned short u16;
typedef __bf16 bf16x8 __attribute__((ext_vector_type(8)));
typedef unsigned short u16x8 __attribute__((ext_vector_type(8)));
typedef float f32x4 __attribute__((ext_vector_type(4)));

#define LOG2E 1.4426950408889634f
#define SCALE_F 0.07216878364870323f   // 1/sqrt(128+64)

__device__ __forceinline__ f32x4 mfma16(bf16x8 a, bf16x8 b, f32x4 c) {
  return __builtin_amdgcn_mfma_f32_16x16x32_bf16(a, b, c, 0, 0, 0);
}

__device__ __forceinline__ u16 f2bf(float f) {
  union { float f; unsigned u; } x; x.f = f;
  unsigned r = x.u + 0x7fffu + ((x.u >> 16) & 1u);  // RNE
  return (u16)(r >> 16);
}
__device__ __forceinline__ float bf2f(u16 v) {
  union { unsigned u; float f; } x; x.u = ((unsigned)v) << 16;
  return x.f;
}

// ---------------------------------------------------------------------------
// RMSNorm: one 256-thread block per row of 2048 fp32. Output bf16.
// ---------------------------------------------------------------------------
__global__ __launch_bounds__(256) void rmsnorm_k(const float* __restrict__ x,
                                                 const float* __restrict__ g,
                                                 u16* __restrict__ out) {
  const int row = blockIdx.x;
  const int t = threadIdx.x;
  const float* xr = x + (size_t)row * 2048;
  float4 a = ((const float4*)xr)[t * 2];
  float4 b = ((const float4*)xr)[t * 2 + 1];
  float ss = a.x*a.x + a.y*a.y + a.z*a.z + a.w*a.w
           + b.x*b.x + b.y*b.y + b.z*b.z + b.w*b.w;
  #pragma unroll
  for (int off = 32; off; off >>= 1) ss += __shfl_xor(ss, off, 64);
  __shared__ float w4[4];
  if ((t & 63) == 0) w4[t >> 6] = ss;
  __syncthreads();
  ss = w4[0] + w4[1] + w4[2] + w4[3];
  const float n = rsqrtf(ss * (1.0f / 2048.0f) + 1e-6f);
  const float* gr = g + t * 8;
  u16x8 o;
  o[0] = f2bf(a.x * n * gr[0]); o[1] = f2bf(a.y * n * gr[1]);
  o[2] = f2bf(a.z * n * gr[2]); o[3] = f2bf(a.w * n * gr[3]);
  o[4] = f2bf(b.x * n * gr[4]); o[5] = f2bf(b.y * n * gr[5]);
  o[6] = f2bf(b.z * n * gr[6]); o[7] = f2bf(b.w * n * gr[7]);
  *(u16x8*)&out[(size_t)row * 2048 + t * 8] = o;
}

// ---------------------------------------------------------------------------
// Transpose-convert fp32 (R x C slab, row stride ldin) -> bf16 (C x R).
// ---------------------------------------------------------------------------
__global__ __launch_bounds__(256) void conv_t(const float* __restrict__ in,
                                              u16* __restrict__ out,
                                              int R, int C, int ldin) {
  __shared__ float tile[64][65];
  const int r0 = blockIdx.y * 64, c0 = blockIdx.x * 64;
  const int tr = threadIdx.x >> 6, tc = threadIdx.x & 63;
  #pragma unroll
  for (int i = 0; i < 16; ++i) {
    int rr = tr * 16 + i;
    tile[rr][tc] = in[(size_t)(r0 + rr) * ldin + c0 + tc];
  }
  __syncthreads();
  #pragma unroll
  for (int i = 0; i < 16; ++i) {
    int rr = tr * 16 + i;
    out[(size_t)(c0 + rr) * R + r0 + tc] = f2bf(tile[tc][rr]);
  }
}

// bf16 (R x C) -> bf16 (C x R), batched over blockIdx.z (stride R*C).
__global__ __launch_bounds__(256) void transpose_bf16(const u16* __restrict__ in,
                                                      u16* __restrict__ out,
                                                      int R, int C) {
  __shared__ u16 tile[64][65];
  const size_t zoff = (size_t)blockIdx.z * R * C;
  const u16* inz = in + zoff;
  u16* outz = out + zoff;
  const int r0 = blockIdx.y * 64, c0 = blockIdx.x * 64;
  const int tr = threadIdx.x >> 6, tc = threadIdx.x & 63;
  #pragma unroll
  for (int i = 0; i < 16; ++i) {
    int rr = tr * 16 + i;
    tile[rr][tc] = inz[(size_t)(r0 + rr) * C + c0 + tc];
  }
  __syncthreads();
  #pragma unroll
  for (int i = 0; i < 16; ++i) {
    int rr = tr * 16 + i;
    outz[(size_t)(c0 + rr) * R + r0 + tc] = tile[tc][rr];
  }
}

// ---------------------------------------------------------------------------
// RoPE in-place on cols [128,192) of a (B*NH, 2048, 192) bf16 buffer.
// idx bits: [0..4]=pair i, [5..15]=pos, [16..20]=bh.
// ---------------------------------------------------------------------------
__global__ __launch_bounds__(256) void rope_k(u16* __restrict__ buf) {
  const int idx = blockIdx.x * 256 + threadIdx.x;
  const int i = idx & 31;
  const int pos = (idx >> 5) & 2047;
  const int bh = idx >> 16;            // 0..31
  u16* p = buf + ((size_t)(bh * 2048 + pos)) * 192 + 128 + 2 * i;
  const float inv = exp2f(-(float)(2 * i) * (19.931568569324174f / 64.0f));
  const float f = (float)pos * inv;
  const float c = cosf(f), s = sinf(f);
  const float x1 = bf2f(p[0]), x2 = bf2f(p[1]);
  p[0] = f2bf(x1 * c - x2 * s);
  p[1] = f2bf(x2 * c + x1 * s);
}

// ---------------------------------------------------------------------------
// Generic bf16 GEMM: C(MxN) = A(MxK,row-major) * Bt(NxK,row-major)^T.
// 256 threads, 128x128 tile, BK=32. Epilogues:
//  0: bf16 row-major out
//  1: *SCALE, Q_C head-split -> out[((b*16+h)*2048+m)*192 + d]    (d=gn&127)
//  2: *SCALE, Q_R head-split -> ... *192 + 128 + d                (d=gn&63)
//  3: K_C head-split          4: K_R head-split
//  5: V head-split -> out[((b*16+h)*2048+m)*128 + d]
//  6: fp32 out = acc + aux(fp32)
//  7: bf16 out = silu(aux_bf16) * acc
// ---------------------------------------------------------------------------
template <int EPI>
__global__ __launch_bounds__(256) void gemm_bt(const u16* __restrict__ A,
                                               const u16* __restrict__ Bt,
                                               int N, int K,
                                               void* __restrict__ outp,
                                               const void* __restrict__ auxp) {
  __shared__ __attribute__((aligned(16))) u16 As[128 * 40];
  __shared__ __attribute__((aligned(16))) u16 Bs[128 * 40];
  const int t = threadIdx.x;
  const int wv = t >> 6, quad = (t >> 4) & 3, ln = t & 15;
  const int bm0 = blockIdx.y * 128, bn0 = blockIdx.x * 128;
  const int wm = (wv >> 1) * 64, wn = (wv & 1) * 64;

  f32x4 acc[4][4] = {};

  const int srow = t >> 2;           // 0..63
  const int sc = (t & 3) * 8;        // 0,8,16,24

  for (int kk = 0; kk < K; kk += 32) {
    #pragma unroll
    for (int i = 0; i < 2; ++i) {
      const int row = i * 64 + srow;
      *(u16x8*)&As[row * 40 + sc] =
          *(const u16x8*)&A[(size_t)(bm0 + row) * K + kk + sc];
      *(u16x8*)&Bs[row * 40 + sc] =
          *(const u16x8*)&Bt[(size_t)(bn0 + row) * K + kk + sc];
    }
    __syncthreads();
    bf16x8 af[4], bfr[4];
    #pragma unroll
    for (int mt = 0; mt < 4; ++mt)
      af[mt] = *(const bf16x8*)&As[(wm + mt * 16 + ln) * 40 + quad * 8];
    #pragma unroll
    for (int nt = 0; nt < 4; ++nt)
      bfr[nt] = *(const bf16x8*)&Bs[(wn + nt * 16 + ln) * 40 + quad * 8];
    #pragma unroll
    for (int mt = 0; mt < 4; ++mt)
      #pragma unroll
      for (int nt = 0; nt < 4; ++nt)
        acc[mt][nt] = mfma16(af[mt], bfr[nt], acc[mt][nt]);
    __syncthreads();
  }

  // epilogue: C row = bm0+wm+mt*16+quad*4+r, col = bn0+wn+nt*16+ln
  #pragma unroll
  for (int mt = 0; mt < 4; ++mt) {
    #pragma unroll
    for (int r = 0; r < 4; ++r) {
      const int gm = bm0 + wm + mt * 16 + quad * 4 + r;
      #pragma unroll
      for (int nt = 0; nt < 4; ++nt) {
        const int gn = bn0 + wn + nt * 16 + ln;
        float v = acc[mt][nt][r];
        if constexpr (EPI == 0) {
          ((u16*)outp)[(size_t)gm * N + gn] = f2bf(v);
        } else if constexpr (EPI >= 1 && EPI <= 4) {
          if constexpr (EPI == 1 || EPI == 2) v *= SCALE_F;
          const int bb = gm >> 11, mm = gm & 2047;
          int h, d, off;
          if constexpr (EPI == 1 || EPI == 3) { h = gn >> 7; d = gn & 127; off = 0; }
          else                                { h = gn >> 6; d = gn & 63; off = 128; }
          ((u16*)outp)[((size_t)((bb * 16 + h) * 2048 + mm)) * 192 + off + d] = f2bf(v);
        } else if constexpr (EPI == 5) {
          const int bb = gm >> 11, mm = gm & 2047;
          const int h = gn >> 7, d = gn & 127;
          ((u16*)outp)[((size_t)((bb * 16 + h) * 2048 + mm)) * 128 + d] = f2bf(v);
        } else if constexpr (EPI == 6) {
          ((float*)outp)[(size_t)gm * N + gn] =
              v + ((const float*)auxp)[(size_t)gm * N + gn];
        } else if constexpr (EPI == 7) {
          const float g = bf2f(((const u16*)auxp)[(size_t)gm * N + gn]);
          const float s = g / (1.0f + __expf(-g));
          ((u16*)outp)[(size_t)gm * N + gn] = f2bf(s * v);
        }
      }
    }
  }
}

// ---------------------------------------------------------------------------
// Flash attention. Q,K:(B*NH, 2048, 192) bf16 (Q pre-scaled, tails rope'd).
// VT:(B*NH, 128, 2048) bf16. O:(B, 2048, NH*128) bf16.
// 256 thr / 4 waves, 64 Q rows per block, wave owns 16 rows.
// ---------------------------------------------------------------------------
__global__ __launch_bounds__(256) void flash_k(const u16* __restrict__ Q,
                                               const u16* __restrict__ K,
                                               const u16* __restrict__ VT,
                                               u16* __restrict__ O) {
  __shared__ __attribute__((aligned(16))) u16 Ks[64 * 200];
  __shared__ __attribute__((aligned(16))) u16 Vt[128 * 72];
  __shared__ __attribute__((aligned(16))) u16 Ps[4][16 * 72];

  const int t = threadIdx.x;
  const int wv = t >> 6, quad = (t >> 4) & 3, ln = t & 15;
  const int b = blockIdx.z, h = blockIdx.y;
  const int m0 = blockIdx.x * 64;
  const size_t qbase = ((size_t)(b * 16 + h)) * 2048;
  const size_t vbase = ((size_t)(b * 16 + h)) * 128;

  bf16x8 qf[6];
  {
    const u16* qp = Q + (qbase + m0 + wv * 16 + ln) * 192;
    #pragma unroll
    for (int ks = 0; ks < 6; ++ks)
      qf[ks] = *(const bf16x8*)&qp[ks * 32 + quad * 8];
  }

  float m_i[4], l_i[4];
  #pragma unroll
  for (int r = 0; r < 4; ++r) { m_i[r] = -1e30f; l_i[r] = 0.0f; }
  f32x4 of[8] = {};

  for (int j = 0; j < 2048 / 64; ++j) {
    #pragma unroll
    for (int i = 0; i < 6; ++i) {
      const int f = i * 256 + t;
      const int row = f / 24, c = (f % 24) * 8;
      *(u16x8*)&Ks[row * 200 + c] =
          *(const u16x8*)&K[(qbase + j * 64 + row) * 192 + c];
    }
    #pragma unroll
    for (int i = 0; i < 4; ++i) {
      const int f = i * 256 + t;
      const int d = f >> 3, rc = (f & 7) * 8;
      *(u16x8*)&Vt[d * 72 + rc] =
          *(const u16x8*)&VT[(vbase + d) * 2048 + j * 64 + rc];
    }
    __syncthreads();

    f32x4 sf[4];
    #pragma unroll
    for (int nt = 0; nt < 4; ++nt) {
      f32x4 s = {0.f, 0.f, 0.f, 0.f};
      #pragma unroll
      for (int ks = 0; ks < 6; ++ks) {
        bf16x8 kb = *(const bf16x8*)&Ks[(nt * 16 + ln) * 200 + ks * 32 + quad * 8];
        s = mfma16(qf[ks], kb, s);
      }
      sf[nt] = s;
    }

    float alpha[4];
    #pragma unroll
    for (int r = 0; r < 4; ++r) {
      float mx = fmaxf(fmaxf(sf[0][r], sf[1][r]), fmaxf(sf[2][r], sf[3][r]));
      #pragma unroll
      for (int off = 8; off; off >>= 1) mx = fmaxf(mx, __shfl_xor(mx, off, 64));
      const float mn = fmaxf(m_i[r], mx);
      alpha[r] = exp2f((m_i[r] - mn) * LOG2E);
      m_i[r] = mn;
      float rs = 0.0f;
      #pragma unroll
      for (int nt = 0; nt < 4; ++nt) {
        const float p = exp2f((sf[nt][r] - mn) * LOG2E);
        sf[nt][r] = p;
        rs += p;
      }
      #pragma unroll
      for (int off = 8; off; off >>= 1) rs += __shfl_xor(rs, off, 64);
      l_i[r] = l_i[r] * alpha[r] + rs;
    }
    #pragma unroll
    for (int dt = 0; dt < 8; ++dt)
      #pragma unroll
      for (int r = 0; r < 4; ++r) of[dt][r] *= alpha[r];

    #pragma unroll
    for (int nt = 0; nt < 4; ++nt)
      #pragma unroll
      for (int r = 0; r < 4; ++r)
        Ps[wv][(quad * 4 + r) * 72 + nt * 16 + ln] = f2bf(sf[nt][r]);
    asm volatile("s_waitcnt lgkmcnt(0)" ::: "memory");

    #pragma unroll
    for (int kt = 0; kt < 2; ++kt) {
      bf16x8 pa = *(const bf16x8*)&Ps[wv][ln * 72 + kt * 32 + quad * 8];
      #pragma unroll
      for (int dt = 0; dt < 8; ++dt) {
        bf16x8 vb = *(const bf16x8*)&Vt[(dt * 16 + ln) * 72 + kt * 32 + quad * 8];
        of[dt] = mfma16(pa, vb, of[dt]);
      }
    }
    __syncthreads();
  }

  #pragma unroll
  for (int dt = 0; dt < 8; ++dt)
    #pragma unroll
    for (int r = 0; r < 4; ++r) {
      const float v = of[dt][r] / l_i[r];
      O[((size_t)(b * 2048 + m0 + wv * 16 + quad * 4 + r)) * 2048 +
        h * 128 + dt * 16 + ln] = f2bf(v);
    }
}

// ---------------------------------------------------------------------------
// Launch. Workspace layout (MiB offsets), phase-aliased, peak 104 MiB:
//   [0,16)  qn      -> VT (after V proj)      -> xn (after flash)
//   [16,32) kvn     -> attn (after V proj)    -> ghalf[16,48) (after out-proj)
//   [32,56) Qb                                   (ghalf/wtf reuse Qb/Kb space)
//   [56,80) Kb      -> wtf [48,64) in FFN phase
//   [80,96) Vb      -> x [64,96) (after flash)
//   [96,104) wt (proj/w_o weight slab, 8 MiB)
// ---------------------------------------------------------------------------
extern "C" void kernel_launch(void* const* d_in, const int* in_sizes, int n_in,
                              void* d_out, int out_size, void* d_ws, size_t ws_size,
                              hipStream_t stream) {
  const float* query     = (const float*)d_in[0];
  const float* key_value = (const float*)d_in[1];
  const float* g_q       = (const float*)d_in[2];
  const float* g_kv      = (const float*)d_in[3];
  const float* g_ffn     = (const float*)d_in[4];
  const float* w_qc      = (const float*)d_in[5];
  const float* w_kc      = (const float*)d_in[6];
  const float* w_qr      = (const float*)d_in[7];
  const float* w_kr      = (const float*)d_in[8];
  const float* w_v       = (const float*)d_in[9];
  const float* w_o       = (const float*)d_in[10];
  const float* w_gate    = (const float*)d_in[11];
  const float* w_up      = (const float*)d_in[12];
  const float* w_down    = (const float*)d_in[13];

  char* ws = (char*)d_ws;
  const size_t MiB = 1048576;
  u16*   qn   = (u16*)(ws + 0 * MiB);
  u16*   kvn  = (u16*)(ws + 16 * MiB);
  u16*   Qb   = (u16*)(ws + 32 * MiB);
  u16*   Kb   = (u16*)(ws + 56 * MiB);
  u16*   Vb   = (u16*)(ws + 80 * MiB);
  u16*   wt   = (u16*)(ws + 96 * MiB);   // 8 MiB slab (proj weights)
  u16*   VT   = (u16*)(ws + 0 * MiB);    // over qn (dead)
  u16*   attn = (u16*)(ws + 16 * MiB);   // over kvn (dead)
  float* x    = (float*)(ws + 64 * MiB); // over Kb-tail+Vb (dead)
  u16*   xn   = (u16*)(ws + 0 * MiB);    // over VT (dead)
  u16*   ghalf= (u16*)(ws + 16 * MiB);   // over attn+Qb-head (dead), 32 MiB
  u16*   wtf  = (u16*)(ws + 48 * MiB);   // over Qb-tail+Kb-head (dead), 16 MiB

  const dim3 blk(256);

  // input norms
  rmsnorm_k<<<4096, blk, 0, stream>>>(query, g_q, qn);
  rmsnorm_k<<<4096, blk, 0, stream>>>(key_value, g_kv, kvn);

  // Q projections (qn dead after these)
  conv_t<<<dim3(32, 32), blk, 0, stream>>>(w_qc, wt, 2048, 2048, 2048);
  gemm_bt<1><<<dim3(16, 32), blk, 0, stream>>>(qn, wt, 2048, 2048, Qb, nullptr);
  conv_t<<<dim3(16, 32), blk, 0, stream>>>(w_qr, wt, 2048, 1024, 1024);
  gemm_bt<2><<<dim3(8, 32), blk, 0, stream>>>(qn, wt, 1024, 2048, Qb, nullptr);
  // K projections
  conv_t<<<dim3(32, 32), blk, 0, stream>>>(w_kc, wt, 2048, 2048, 2048);
  gemm_bt<3><<<dim3(16, 32), blk, 0, stream>>>(kvn, wt, 2048, 2048, Kb, nullptr);
  conv_t<<<dim3(16, 32), blk, 0, stream>>>(w_kr, wt, 2048, 1024, 1024);
  gemm_bt<4><<<dim3(8, 32), blk, 0, stream>>>(kvn, wt, 1024, 2048, Kb, nullptr);
  // V projection (kvn dead after)
  conv_t<<<dim3(32, 32), blk, 0, stream>>>(w_v, wt, 2048, 2048, 2048);
  gemm_bt<5><<<dim3(16, 32), blk, 0, stream>>>(kvn, wt, 2048, 2048, Vb, nullptr);

  // RoPE tails
  rope_k<<<8192, blk, 0, stream>>>(Qb);
  rope_k<<<8192, blk, 0, stream>>>(Kb);

  // V -> V^T per head (Vb -> VT; VT aliases dead qn)
  transpose_bf16<<<dim3(2, 32, 32), blk, 0, stream>>>(Vb, VT, 2048, 128);

  // flash attention -> attn (aliases dead kvn)
  flash_k<<<dim3(32, 16, 2), blk, 0, stream>>>(Qb, Kb, VT, attn);

  // out projection + residual -> x fp32 (aliases dead Kb-tail/Vb)
  conv_t<<<dim3(32, 32), blk, 0, stream>>>(w_o, wt, 2048, 2048, 2048);
  gemm_bt<6><<<dim3(16, 32), blk, 0, stream>>>(attn, wt, 2048, 2048, x, query);

  // FFN: rmsnorm then two N=4096 halves with split-K accumulation into d_out
  rmsnorm_k<<<4096, blk, 0, stream>>>(x, g_ffn, xn);
  for (int h = 0; h < 2; ++h) {
    const int n0 = h * 4096;
    // gate half: w_gate[:, n0:n0+4096]^T -> wtf (4096 x 2048)
    conv_t<<<dim3(64, 32), blk, 0, stream>>>(w_gate + n0, wtf, 2048, 4096, 8192);
    gemm_bt<0><<<dim3(32, 32), blk, 0, stream>>>(xn, wtf, 4096, 2048, ghalf, nullptr);
    // up half, combine: ghalf = silu(gate) * up
    conv_t<<<dim3(64, 32), blk, 0, stream>>>(w_up + n0, wtf, 2048, 4096, 8192);
    gemm_bt<7><<<dim3(32, 32), blk, 0, stream>>>(xn, wtf, 4096, 2048, ghalf, ghalf);
    // down half: w_down[n0:n0+4096, :]^T -> wtf (2048 x 4096)
    conv_t<<<dim3(32, 64), blk, 0, stream>>>(w_down + (size_t)n0 * 2048, wtf,
                                             4096, 2048, 2048);
    gemm_bt<6><<<dim3(16, 32), blk, 0, stream>>>(ghalf, wtf, 2048, 4096,
                                                 (float*)d_out,
                                                 h == 0 ? (const void*)x
                                                        : (const void*)d_out);
  }
}

// Round 3
// 1552.826 us; speedup vs baseline: 1.0092x; 1.0092x over previous
//
#include <hip/hip_runtime.h>
#include <stdint.h>

// ---------------------------------------------------------------------------
// AttentionBlock (MLA-style) on gfx950. Round 3: m97-class GEMM staging —
// __builtin_amdgcn_global_load_lds width=16, unpadded 128x32 LDS tiles.
// (R2 passed at 1567us; GEMM aggregate ~1.1ms was the dominant cost.)
// ---------------------------------------------------------------------------

typedef unsigned short u16;
typedef __bf16 bf16x8 __attribute__((ext_vector_type(8)));
typedef unsigned short u16x8 __attribute__((ext_vector_type(8)));
typedef float f32x4 __attribute__((ext_vector_type(4)));

#define LOG2E 1.4426950408889634f
#define SCALE_F 0.07216878364870323f   // 1/sqrt(128+64)

__device__ __forceinline__ f32x4 mfma16(bf16x8 a, bf16x8 b, f32x4 c) {
  return __builtin_amdgcn_mfma_f32_16x16x32_bf16(a, b, c, 0, 0, 0);
}

__device__ __forceinline__ u16 f2bf(float f) {
  union { float f; unsigned u; } x; x.f = f;
  unsigned r = x.u + 0x7fffu + ((x.u >> 16) & 1u);  // RNE
  return (u16)(r >> 16);
}
__device__ __forceinline__ float bf2f(u16 v) {
  union { unsigned u; float f; } x; x.u = ((unsigned)v) << 16;
  return x.f;
}

// async global->LDS, 16 bytes per lane. LDS side must be contiguous in lane
// order (wave-uniform base + lane*16) — caller guarantees.
__device__ __forceinline__ void gload_lds16(const u16* g, u16* l) {
  __builtin_amdgcn_global_load_lds(
      (const __attribute__((address_space(1))) unsigned int*)g,
      (__attribute__((address_space(3))) unsigned int*)l, 16, 0, 0);
}

// ---------------------------------------------------------------------------
// RMSNorm: one 256-thread block per row of 2048 fp32. Output bf16.
// ---------------------------------------------------------------------------
__global__ __launch_bounds__(256) void rmsnorm_k(const float* __restrict__ x,
                                                 const float* __restrict__ g,
                                                 u16* __restrict__ out) {
  const int row = blockIdx.x;
  const int t = threadIdx.x;
  const float* xr = x + (size_t)row * 2048;
  float4 a = ((const float4*)xr)[t * 2];
  float4 b = ((const float4*)xr)[t * 2 + 1];
  float ss = a.x*a.x + a.y*a.y + a.z*a.z + a.w*a.w
           + b.x*b.x + b.y*b.y + b.z*b.z + b.w*b.w;
  #pragma unroll
  for (int off = 32; off; off >>= 1) ss += __shfl_xor(ss, off, 64);
  __shared__ float w4[4];
  if ((t & 63) == 0) w4[t >> 6] = ss;
  __syncthreads();
  ss = w4[0] + w4[1] + w4[2] + w4[3];
  const float n = rsqrtf(ss * (1.0f / 2048.0f) + 1e-6f);
  const float* gr = g + t * 8;
  u16x8 o;
  o[0] = f2bf(a.x * n * gr[0]); o[1] = f2bf(a.y * n * gr[1]);
  o[2] = f2bf(a.z * n * gr[2]); o[3] = f2bf(a.w * n * gr[3]);
  o[4] = f2bf(b.x * n * gr[4]); o[5] = f2bf(b.y * n * gr[5]);
  o[6] = f2bf(b.z * n * gr[6]); o[7] = f2bf(b.w * n * gr[7]);
  *(u16x8*)&out[(size_t)row * 2048 + t * 8] = o;
}

// ---------------------------------------------------------------------------
// Transpose-convert fp32 (R x C slab, row stride ldin) -> bf16 (C x R).
// ---------------------------------------------------------------------------
__global__ __launch_bounds__(256) void conv_t(const float* __restrict__ in,
                                              u16* __restrict__ out,
                                              int R, int C, int ldin) {
  __shared__ float tile[64][65];
  const int r0 = blockIdx.y * 64, c0 = blockIdx.x * 64;
  const int tr = threadIdx.x >> 6, tc = threadIdx.x & 63;
  #pragma unroll
  for (int i = 0; i < 16; ++i) {
    int rr = tr * 16 + i;
    tile[rr][tc] = in[(size_t)(r0 + rr) * ldin + c0 + tc];
  }
  __syncthreads();
  #pragma unroll
  for (int i = 0; i < 16; ++i) {
    int rr = tr * 16 + i;
    out[(size_t)(c0 + rr) * R + r0 + tc] = f2bf(tile[tc][rr]);
  }
}

// bf16 (R x C) -> bf16 (C x R), batched over blockIdx.z (stride R*C).
__global__ __launch_bounds__(256) void transpose_bf16(const u16* __restrict__ in,
                                                      u16* __restrict__ out,
                                                      int R, int C) {
  __shared__ u16 tile[64][65];
  const size_t zoff = (size_t)blockIdx.z * R * C;
  const u16* inz = in + zoff;
  u16* outz = out + zoff;
  const int r0 = blockIdx.y * 64, c0 = blockIdx.x * 64;
  const int tr = threadIdx.x >> 6, tc = threadIdx.x & 63;
  #pragma unroll
  for (int i = 0; i < 16; ++i) {
    int rr = tr * 16 + i;
    tile[rr][tc] = inz[(size_t)(r0 + rr) * C + c0 + tc];
  }
  __syncthreads();
  #pragma unroll
  for (int i = 0; i < 16; ++i) {
    int rr = tr * 16 + i;
    outz[(size_t)(c0 + rr) * R + r0 + tc] = tile[tc][rr];
  }
}

// ---------------------------------------------------------------------------
// RoPE in-place on cols [128,192) of a (B*NH, 2048, 192) bf16 buffer.
// ---------------------------------------------------------------------------
__global__ __launch_bounds__(256) void rope_k(u16* __restrict__ buf) {
  const int idx = blockIdx.x * 256 + threadIdx.x;
  const int i = idx & 31;
  const int pos = (idx >> 5) & 2047;
  const int bh = idx >> 16;            // 0..31
  u16* p = buf + ((size_t)(bh * 2048 + pos)) * 192 + 128 + 2 * i;
  const float inv = exp2f(-(float)(2 * i) * (19.931568569324174f / 64.0f));
  const float f = (float)pos * inv;
  const float c = cosf(f), s = sinf(f);
  const float x1 = bf2f(p[0]), x2 = bf2f(p[1]);
  p[0] = f2bf(x1 * c - x2 * s);
  p[1] = f2bf(x2 * c + x1 * s);
}

// ---------------------------------------------------------------------------
// bf16 GEMM, m97 structure: C(MxN) = A(MxK,rm) * Bt(NxK,rm)^T.
// 256 thr, 128x128 tile, BK=32, global_load_lds width=16 staging into
// unpadded 128x32 LDS tiles. Epilogues as before.
// ---------------------------------------------------------------------------
template <int EPI>
__global__ __launch_bounds__(256) void gemm_bt(const u16* __restrict__ A,
                                               const u16* __restrict__ Bt,
                                               int N, int K,
                                               void* __restrict__ outp,
                                               const void* __restrict__ auxp) {
  __shared__ __attribute__((aligned(16))) u16 As[128 * 32];
  __shared__ __attribute__((aligned(16))) u16 Bs[128 * 32];
  const int t = threadIdx.x;
  const int wv = t >> 6, quad = (t >> 4) & 3, ln = t & 15;
  const int lane = t & 63;
  const int bm0 = blockIdx.y * 128, bn0 = blockIdx.x * 128;
  const int wm = (wv >> 1) * 64, wn = (wv & 1) * 64;

  f32x4 acc[4][4] = {};

  // staging coords: one instruction stages 16 rows (64 lanes x 16B).
  const int r_in = lane >> 2;          // 0..15
  const int c_in = (lane & 3) * 8;     // 0,8,16,24

  for (int kk = 0; kk < K; kk += 32) {
    #pragma unroll
    for (int i = 0; i < 2; ++i) {
      const int row = (i * 4 + wv) * 16 + r_in;
      gload_lds16(&A[(size_t)(bm0 + row) * K + kk + c_in], &As[row * 32 + c_in]);
      gload_lds16(&Bt[(size_t)(bn0 + row) * K + kk + c_in], &Bs[row * 32 + c_in]);
    }
    __syncthreads();
    bf16x8 af[4], bfr[4];
    #pragma unroll
    for (int mt = 0; mt < 4; ++mt)
      af[mt] = *(const bf16x8*)&As[(wm + mt * 16 + ln) * 32 + quad * 8];
    #pragma unroll
    for (int nt = 0; nt < 4; ++nt)
      bfr[nt] = *(const bf16x8*)&Bs[(wn + nt * 16 + ln) * 32 + quad * 8];
    #pragma unroll
    for (int mt = 0; mt < 4; ++mt)
      #pragma unroll
      for (int nt = 0; nt < 4; ++nt)
        acc[mt][nt] = mfma16(af[mt], bfr[nt], acc[mt][nt]);
    __syncthreads();
  }

  // epilogue: C row = bm0+wm+mt*16+quad*4+r, col = bn0+wn+nt*16+ln
  #pragma unroll
  for (int mt = 0; mt < 4; ++mt) {
    #pragma unroll
    for (int r = 0; r < 4; ++r) {
      const int gm = bm0 + wm + mt * 16 + quad * 4 + r;
      #pragma unroll
      for (int nt = 0; nt < 4; ++nt) {
        const int gn = bn0 + wn + nt * 16 + ln;
        float v = acc[mt][nt][r];
        if constexpr (EPI == 0) {
          ((u16*)outp)[(size_t)gm * N + gn] = f2bf(v);
        } else if constexpr (EPI >= 1 && EPI <= 4) {
          if constexpr (EPI == 1 || EPI == 2) v *= SCALE_F;
          const int bb = gm >> 11, mm = gm & 2047;
          int h, d, off;
          if constexpr (EPI == 1 || EPI == 3) { h = gn >> 7; d = gn & 127; off = 0; }
          else                                { h = gn >> 6; d = gn & 63; off = 128; }
          ((u16*)outp)[((size_t)((bb * 16 + h) * 2048 + mm)) * 192 + off + d] = f2bf(v);
        } else if constexpr (EPI == 5) {
          const int bb = gm >> 11, mm = gm & 2047;
          const int h = gn >> 7, d = gn & 127;
          ((u16*)outp)[((size_t)((bb * 16 + h) * 2048 + mm)) * 128 + d] = f2bf(v);
        } else if constexpr (EPI == 6) {
          ((float*)outp)[(size_t)gm * N + gn] =
              v + ((const float*)auxp)[(size_t)gm * N + gn];
        } else if constexpr (EPI == 7) {
          const float g = bf2f(((const u16*)auxp)[(size_t)gm * N + gn]);
          const float s = g / (1.0f + __expf(-g));
          ((u16*)outp)[(size_t)gm * N + gn] = f2bf(s * v);
        }
      }
    }
  }
}

// ---------------------------------------------------------------------------
// Flash attention. Q,K:(B*NH, 2048, 192) bf16 (Q pre-scaled, tails rope'd).
// VT:(B*NH, 128, 2048) bf16. O:(B, 2048, NH*128) bf16.
// 256 thr / 4 waves, 64 Q rows per block, wave owns 16 rows.
// ---------------------------------------------------------------------------
__global__ __launch_bounds__(256) void flash_k(const u16* __restrict__ Q,
                                               const u16* __restrict__ K,
                                               const u16* __restrict__ VT,
                                               u16* __restrict__ O) {
  __shared__ __attribute__((aligned(16))) u16 Ks[64 * 200];
  __shared__ __attribute__((aligned(16))) u16 Vt[128 * 72];
  __shared__ __attribute__((aligned(16))) u16 Ps[4][16 * 72];

  const int t = threadIdx.x;
  const int wv = t >> 6, quad = (t >> 4) & 3, ln = t & 15;
  const int b = blockIdx.z, h = blockIdx.y;
  const int m0 = blockIdx.x * 64;
  const size_t qbase = ((size_t)(b * 16 + h)) * 2048;
  const size_t vbase = ((size_t)(b * 16 + h)) * 128;

  bf16x8 qf[6];
  {
    const u16* qp = Q + (qbase + m0 + wv * 16 + ln) * 192;
    #pragma unroll
    for (int ks = 0; ks < 6; ++ks)
      qf[ks] = *(const bf16x8*)&qp[ks * 32 + quad * 8];
  }

  float m_i[4], l_i[4];
  #pragma unroll
  for (int r = 0; r < 4; ++r) { m_i[r] = -1e30f; l_i[r] = 0.0f; }
  f32x4 of[8] = {};

  for (int j = 0; j < 2048 / 64; ++j) {
    #pragma unroll
    for (int i = 0; i < 6; ++i) {
      const int f = i * 256 + t;
      const int row = f / 24, c = (f % 24) * 8;
      *(u16x8*)&Ks[row * 200 + c] =
          *(const u16x8*)&K[(qbase + j * 64 + row) * 192 + c];
    }
    #pragma unroll
    for (int i = 0; i < 4; ++i) {
      const int f = i * 256 + t;
      const int d = f >> 3, rc = (f & 7) * 8;
      *(u16x8*)&Vt[d * 72 + rc] =
          *(const u16x8*)&VT[(vbase + d) * 2048 + j * 64 + rc];
    }
    __syncthreads();

    f32x4 sf[4];
    #pragma unroll
    for (int nt = 0; nt < 4; ++nt) {
      f32x4 s = {0.f, 0.f, 0.f, 0.f};
      #pragma unroll
      for (int ks = 0; ks < 6; ++ks) {
        bf16x8 kb = *(const bf16x8*)&Ks[(nt * 16 + ln) * 200 + ks * 32 + quad * 8];
        s = mfma16(qf[ks], kb, s);
      }
      sf[nt] = s;
    }

    float alpha[4];
    #pragma unroll
    for (int r = 0; r < 4; ++r) {
      float mx = fmaxf(fmaxf(sf[0][r], sf[1][r]), fmaxf(sf[2][r], sf[3][r]));
      #pragma unroll
      for (int off = 8; off; off >>= 1) mx = fmaxf(mx, __shfl_xor(mx, off, 64));
      const float mn = fmaxf(m_i[r], mx);
      alpha[r] = exp2f((m_i[r] - mn) * LOG2E);
      m_i[r] = mn;
      float rs = 0.0f;
      #pragma unroll
      for (int nt = 0; nt < 4; ++nt) {
        const float p = exp2f((sf[nt][r] - mn) * LOG2E);
        sf[nt][r] = p;
        rs += p;
      }
      #pragma unroll
      for (int off = 8; off; off >>= 1) rs += __shfl_xor(rs, off, 64);
      l_i[r] = l_i[r] * alpha[r] + rs;
    }
    #pragma unroll
    for (int dt = 0; dt < 8; ++dt)
      #pragma unroll
      for (int r = 0; r < 4; ++r) of[dt][r] *= alpha[r];

    #pragma unroll
    for (int nt = 0; nt < 4; ++nt)
      #pragma unroll
      for (int r = 0; r < 4; ++r)
        Ps[wv][(quad * 4 + r) * 72 + nt * 16 + ln] = f2bf(sf[nt][r]);
    asm volatile("s_waitcnt lgkmcnt(0)" ::: "memory");

    #pragma unroll
    for (int kt = 0; kt < 2; ++kt) {
      bf16x8 pa = *(const bf16x8*)&Ps[wv][ln * 72 + kt * 32 + quad * 8];
      #pragma unroll
      for (int dt = 0; dt < 8; ++dt) {
        bf16x8 vb = *(const bf16x8*)&Vt[(dt * 16 + ln) * 72 + kt * 32 + quad * 8];
        of[dt] = mfma16(pa, vb, of[dt]);
      }
    }
    __syncthreads();
  }

  #pragma unroll
  for (int dt = 0; dt < 8; ++dt)
    #pragma unroll
    for (int r = 0; r < 4; ++r) {
      const float v = of[dt][r] / l_i[r];
      O[((size_t)(b * 2048 + m0 + wv * 16 + quad * 4 + r)) * 2048 +
        h * 128 + dt * 16 + ln] = f2bf(v);
    }
}

// ---------------------------------------------------------------------------
// Launch. Workspace layout (MiB offsets), phase-aliased, peak 104 MiB.
// ---------------------------------------------------------------------------
extern "C" void kernel_launch(void* const* d_in, const int* in_sizes, int n_in,
                              void* d_out, int out_size, void* d_ws, size_t ws_size,
                              hipStream_t stream) {
  const float* query     = (const float*)d_in[0];
  const float* key_value = (const float*)d_in[1];
  const float* g_q       = (const float*)d_in[2];
  const float* g_kv      = (const float*)d_in[3];
  const float* g_ffn     = (const float*)d_in[4];
  const float* w_qc      = (const float*)d_in[5];
  const float* w_kc      = (const float*)d_in[6];
  const float* w_qr      = (const float*)d_in[7];
  const float* w_kr      = (const float*)d_in[8];
  const float* w_v       = (const float*)d_in[9];
  const float* w_o       = (const float*)d_in[10];
  const float* w_gate    = (const float*)d_in[11];
  const float* w_up      = (const float*)d_in[12];
  const float* w_down    = (const float*)d_in[13];

  char* ws = (char*)d_ws;
  const size_t MiB = 1048576;
  u16*   qn   = (u16*)(ws + 0 * MiB);
  u16*   kvn  = (u16*)(ws + 16 * MiB);
  u16*   Qb   = (u16*)(ws + 32 * MiB);
  u16*   Kb   = (u16*)(ws + 56 * MiB);
  u16*   Vb   = (u16*)(ws + 80 * MiB);
  u16*   wt   = (u16*)(ws + 96 * MiB);   // 8 MiB slab (proj weights)
  u16*   VT   = (u16*)(ws + 0 * MiB);    // over qn (dead)
  u16*   attn = (u16*)(ws + 16 * MiB);   // over kvn (dead)
  float* x    = (float*)(ws + 64 * MiB); // over Kb-tail+Vb (dead)
  u16*   xn   = (u16*)(ws + 0 * MiB);    // over VT (dead)
  u16*   ghalf= (u16*)(ws + 16 * MiB);   // over attn+Qb-head (dead), 32 MiB
  u16*   wtf  = (u16*)(ws + 48 * MiB);   // over Qb-tail+Kb-head (dead), 16 MiB

  const dim3 blk(256);

  // input norms
  rmsnorm_k<<<4096, blk, 0, stream>>>(query, g_q, qn);
  rmsnorm_k<<<4096, blk, 0, stream>>>(key_value, g_kv, kvn);

  // Q projections (qn dead after these)
  conv_t<<<dim3(32, 32), blk, 0, stream>>>(w_qc, wt, 2048, 2048, 2048);
  gemm_bt<1><<<dim3(16, 32), blk, 0, stream>>>(qn, wt, 2048, 2048, Qb, nullptr);
  conv_t<<<dim3(16, 32), blk, 0, stream>>>(w_qr, wt, 2048, 1024, 1024);
  gemm_bt<2><<<dim3(8, 32), blk, 0, stream>>>(qn, wt, 1024, 2048, Qb, nullptr);
  // K projections
  conv_t<<<dim3(32, 32), blk, 0, stream>>>(w_kc, wt, 2048, 2048, 2048);
  gemm_bt<3><<<dim3(16, 32), blk, 0, stream>>>(kvn, wt, 2048, 2048, Kb, nullptr);
  conv_t<<<dim3(16, 32), blk, 0, stream>>>(w_kr, wt, 2048, 1024, 1024);
  gemm_bt<4><<<dim3(8, 32), blk, 0, stream>>>(kvn, wt, 1024, 2048, Kb, nullptr);
  // V projection (kvn dead after)
  conv_t<<<dim3(32, 32), blk, 0, stream>>>(w_v, wt, 2048, 2048, 2048);
  gemm_bt<5><<<dim3(16, 32), blk, 0, stream>>>(kvn, wt, 2048, 2048, Vb, nullptr);

  // RoPE tails
  rope_k<<<8192, blk, 0, stream>>>(Qb);
  rope_k<<<8192, blk, 0, stream>>>(Kb);

  // V -> V^T per head (Vb -> VT; VT aliases dead qn)
  transpose_bf16<<<dim3(2, 32, 32), blk, 0, stream>>>(Vb, VT, 2048, 128);

  // flash attention -> attn (aliases dead kvn)
  flash_k<<<dim3(32, 16, 2), blk, 0, stream>>>(Qb, Kb, VT, attn);

  // out projection + residual -> x fp32 (aliases dead Kb-tail/Vb)
  conv_t<<<dim3(32, 32), blk, 0, stream>>>(w_o, wt, 2048, 2048, 2048);
  gemm_bt<6><<<dim3(16, 32), blk, 0, stream>>>(attn, wt, 2048, 2048, x, query);

  // FFN: rmsnorm then two N=4096 halves with split-K accumulation into d_out
  rmsnorm_k<<<4096, blk, 0, stream>>>(x, g_ffn, xn);
  for (int h = 0; h < 2; ++h) {
    const int n0 = h * 4096;
    conv_t<<<dim3(64, 32), blk, 0, stream>>>(w_gate + n0, wtf, 2048, 4096, 8192);
    gemm_bt<0><<<dim3(32, 32), blk, 0, stream>>>(xn, wtf, 4096, 2048, ghalf, nullptr);
    conv_t<<<dim3(64, 32), blk, 0, stream>>>(w_up + n0, wtf, 2048, 4096, 8192);
    gemm_bt<7><<<dim3(32, 32), blk, 0, stream>>>(xn, wtf, 4096, 2048, ghalf, ghalf);
    conv_t<<<dim3(32, 64), blk, 0, stream>>>(w_down + (size_t)n0 * 2048, wtf,
                                             4096, 2048, 2048);
    gemm_bt<6><<<dim3(16, 32), blk, 0, stream>>>(ghalf, wtf, 2048, 4096,
                                                 (float*)d_out,
                                                 h == 0 ? (const void*)x
                                                        : (const void*)d_out);
  }
}